// Round 9
// baseline (104.741 us; speedup 1.0000x reference)
//
#include <hip/hip_runtime.h>
#include <stdint.h>

#define IN_DIM  4096
#define OUT_DIM 4096
#define BATCH   4096
#define NACT    32

typedef float          f32x4  __attribute__((ext_vector_type(4)));
typedef unsigned short u16x4  __attribute__((ext_vector_type(4)));

// round-to-nearest f32 -> bf16
__device__ inline unsigned short f2bf(float f) {
    unsigned u = __float_as_uint(f);
    u += 0x7FFF + ((u >> 16) & 1);
    return (unsigned short)(u >> 16);
}

// ---------------------------------------------------------------------------
// Fused prep kernel (measured ~27us ~= its 160MB/6.3TB/s roofline).
//   blocks [0, OUT_DIM)              : compress mask+weight -> idx/w tables
//   blocks [OUT_DIM, OUT_DIM+4096)   : transpose x -> xT bf16 [IN_DIM][BATCH]
// ---------------------------------------------------------------------------
__global__ __launch_bounds__(256)
void prep_kernel(const float* __restrict__ weight,
                 const int*   __restrict__ mask,
                 const float* __restrict__ x,
                 int*         __restrict__ idx_tab,
                 float*       __restrict__ w_tab,
                 unsigned short* __restrict__ xT) {
    __shared__ float tile[64][65];        // transpose tile; aliased as scan[]
    int* scan = (int*)&tile[0][0];
    const int t = threadIdx.x;

    if (blockIdx.x < OUT_DIM) {
        // ---- compress: one block per output row ----
        const int o = blockIdx.x;
        const int* mrow = mask + (size_t)o * IN_DIM;
        const int  base = t * 16;

        int m[16];
        const int4* m4 = (const int4*)(mrow + base);
        #pragma unroll
        for (int j = 0; j < 4; ++j) {
            int4 v = m4[j];
            m[j*4+0] = v.x; m[j*4+1] = v.y; m[j*4+2] = v.z; m[j*4+3] = v.w;
        }
        int c = 0;
        #pragma unroll
        for (int j = 0; j < 16; ++j) c += (m[j] != 0);

        scan[t] = c;
        __syncthreads();
        for (int off = 1; off < 256; off <<= 1) {
            int add = (t >= off) ? scan[t - off] : 0;
            __syncthreads();
            scan[t] += add;
            __syncthreads();
        }
        int pos = scan[t] - c;            // exclusive prefix
        for (int j = 0; j < 16; ++j) {
            if (m[j] != 0) {
                int idx = base + j;
                idx_tab[o * NACT + pos] = idx;
                w_tab [o * NACT + pos] = weight[(size_t)o * IN_DIM + idx];
                ++pos;
            }
        }
    } else {
        // ---- transpose + bf16 quantize: 64x64 tile ----
        const int q  = blockIdx.x - OUT_DIM;
        const int bi = q & 63;            // batch tile
        const int bj = q >> 6;            // in-dim tile
        {
            const int c  = (t & 15) * 4;
            const int r0 = t >> 4;
            #pragma unroll
            for (int p = 0; p < 4; ++p) {
                int r = r0 + p * 16;
                float4 v = *(const float4*)(x + (size_t)(bi*64 + r) * IN_DIM + bj*64 + c);
                tile[r][c+0] = v.x; tile[r][c+1] = v.y;
                tile[r][c+2] = v.z; tile[r][c+3] = v.w;
            }
        }
        __syncthreads();
        {
            const int b4 = (t & 15) * 4;
            const int j0 = t >> 4;
            #pragma unroll
            for (int p = 0; p < 4; ++p) {
                int j = j0 + p * 16;
                u16x4 v = { f2bf(tile[b4+0][j]), f2bf(tile[b4+1][j]),
                            f2bf(tile[b4+2][j]), f2bf(tile[b4+3][j]) };
                *(u16x4*)(xT + (size_t)(bj*64 + j) * BATCH + bi*64 + b4) = v;
            }
        }
    }
}

// ---------------------------------------------------------------------------
// Main sparse matmul.
// Block = 128 threads, ZERO LDS; thread t = batches (2t, 2t+1) x 16 outputs.
// Slab = 256 batches x 4096 rows x 2B = 2 MB (proven L2-resident r7/r8,
// FETCH ~= compulsory). Gathers are dword loads: one load + <<16 /
// &0xFFFF0000 serves TWO batches (r8: halved the load/addr-VALU stall).
// o is wave-uniform -> idx/w/bias are scalar s_loads.
// Store: plain float4 (write-allocate). Round 3 proved this pattern merges
// in L2 to 1.16x write amp; the 2 MB slab leaves ~2 MB L2 slack for the
// ~16KB/block transient write stream (unlike r6's zero-slack 4MB slab).
// Dropping the r8 LDS restage removes the 17.4KB/block occupancy cap
// (9 blocks/CU -> grid-capped 16 blocks/CU) and a barrier.
// Grid = 16 slabs x 256 o-tiles; swizzle: each XCD sweeps o-tiles slab-major.
// ---------------------------------------------------------------------------
__global__ __launch_bounds__(128)
void spmm_kernel(const unsigned short* __restrict__ xT,
                 const int*   __restrict__ idx_tab,
                 const float* __restrict__ w_tab,
                 const float* __restrict__ bias,
                 float*       __restrict__ out) {
    const int t   = threadIdx.x;          // 0..127
    const int bid = blockIdx.x;           // 4096 blocks
    const int v    = (bid & 7) * 512 + (bid >> 3);   // bijective XCD swizzle
    const int slab = v >> 8;              // 0..15 (slab-major per XCD)
    const int ot   = v & 255;             // o-tile minor
    const int o0   = ot * 16;
    const int b0   = slab * 256;          // slab batch base
    const int bl   = t * 2;               // batch-local (even)

    const unsigned short* xb = xT + b0 + bl;   // u16x2 at xb[i*BATCH]

    float acc0[16], acc1[16];
    #pragma unroll 2
    for (int o = 0; o < 16; ++o) {
        const int*   ip = idx_tab + (size_t)(o0 + o) * NACT;   // wave-uniform
        const float* wp = w_tab   + (size_t)(o0 + o) * NACT;   // -> s_load
        float a00 = 0.f, a01 = 0.f, a10 = 0.f, a11 = 0.f;
        #pragma unroll
        for (int k = 0; k < NACT; k += 2) {
            unsigned u0 = *(const unsigned*)(xb + (size_t)ip[k]   * BATCH);
            unsigned u1 = *(const unsigned*)(xb + (size_t)ip[k+1] * BATCH);
            float x00 = __uint_as_float(u0 << 16);          // batch bl
            float x01 = __uint_as_float(u0 & 0xFFFF0000u);  // batch bl+1
            float x10 = __uint_as_float(u1 << 16);
            float x11 = __uint_as_float(u1 & 0xFFFF0000u);
            a00 = fmaf(wp[k],   x00, a00);
            a01 = fmaf(wp[k],   x01, a01);
            a10 = fmaf(wp[k+1], x10, a10);
            a11 = fmaf(wp[k+1], x11, a11);
        }
        const float bo = bias[o0 + o];
        acc0[o] = (a00 + a10) - bo;
        acc1[o] = (a01 + a11) - bo;
    }

    // ---- direct full-tile stores: 2 batches x 16 consecutive outputs ----
    float* op0 = out + (size_t)(b0 + bl) * OUT_DIM + o0;
    float* op1 = op0 + OUT_DIM;
    #pragma unroll
    for (int q = 0; q < 4; ++q) {
        f32x4 r0v = { acc0[q*4+0], acc0[q*4+1], acc0[q*4+2], acc0[q*4+3] };
        f32x4 r1v = { acc1[q*4+0], acc1[q*4+1], acc1[q*4+2], acc1[q*4+3] };
        *(f32x4*)(op0 + q*4) = r0v;
        *(f32x4*)(op1 + q*4) = r1v;
    }
}

// ---------------------------------------------------------------------------
// Fallback A (ws >= table only): gathers from x directly (uncoalesced, correct).
// ---------------------------------------------------------------------------
__global__ __launch_bounds__(256)
void spmm_noT_kernel(const float* __restrict__ x,
                     const int*   __restrict__ idx_tab,
                     const float* __restrict__ w_tab,
                     const float* __restrict__ bias,
                     float*       __restrict__ out) {
    const int t   = threadIdx.x;
    const int bid = blockIdx.x;           // 4096 blocks
    const int slab = bid >> 8;
    const int ot   = bid & 255;
    const int o0   = ot * 16;
    const int b    = slab * 256 + t;

    float acc[16];
    #pragma unroll 1
    for (int o = 0; o < 16; ++o) {
        const int*   ip = idx_tab + (size_t)(o0 + o) * NACT;
        const float* wp = w_tab   + (size_t)(o0 + o) * NACT;
        float a = 0.f;
        for (int k = 0; k < NACT; ++k)
            a = fmaf(wp[k], x[(size_t)b * IN_DIM + ip[k]], a);
        acc[o] = a - bias[o0 + o];
    }
    float* op = out + (size_t)b * OUT_DIM + o0;
    #pragma unroll
    for (int q = 0; q < 4; ++q) {
        float4 r; r.x = acc[q*4+0]; r.y = acc[q*4+1];
                  r.z = acc[q*4+2]; r.w = acc[q*4+3];
        *(float4*)(op + q*4) = r;
    }
}

// ---------------------------------------------------------------------------
// Fallback B (tiny ws): block per output row; inline compress into LDS.
// ---------------------------------------------------------------------------
__global__ __launch_bounds__(256)
void naive_kernel(const float* __restrict__ x,
                  const float* __restrict__ weight,
                  const float* __restrict__ bias,
                  const int*   __restrict__ mask,
                  float*       __restrict__ out) {
    const int o = blockIdx.x;
    const int t = threadIdx.x;
    __shared__ int   scan[256];
    __shared__ int   sidx[NACT];
    __shared__ float sw[NACT];

    const int* mrow = mask + (size_t)o * IN_DIM;
    const int  base = t * 16;
    int c = 0;
    #pragma unroll
    for (int j = 0; j < 16; ++j) c += (mrow[base + j] != 0);
    scan[t] = c;
    __syncthreads();
    for (int off = 1; off < 256; off <<= 1) {
        int add = (t >= off) ? scan[t - off] : 0;
        __syncthreads();
        scan[t] += add;
        __syncthreads();
    }
    int pos = scan[t] - c;
    for (int j = 0; j < 16; ++j) {
        if (mrow[base + j] != 0) {
            sidx[pos] = base + j;
            sw[pos]   = weight[(size_t)o * IN_DIM + base + j];
            ++pos;
        }
    }
    __syncthreads();
    const float bo = bias[o];
    for (int b = t; b < BATCH; b += 256) {
        float a = 0.f;
        #pragma unroll
        for (int k = 0; k < NACT; ++k)
            a = fmaf(sw[k], x[(size_t)b * IN_DIM + sidx[k]], a);
        out[(size_t)b * OUT_DIM + o] = a - bo;
    }
}

// ---------------------------------------------------------------------------
extern "C" void kernel_launch(void* const* d_in, const int* in_sizes, int n_in,
                              void* d_out, int out_size, void* d_ws, size_t ws_size,
                              hipStream_t stream) {
    const float* x      = (const float*)d_in[0];
    const float* weight = (const float*)d_in[1];
    const float* bias   = (const float*)d_in[2];
    const int*   mask   = (const int*)  d_in[3];
    float* out = (float*)d_out;

    const size_t TAB_BYTES  = (size_t)OUT_DIM * NACT * (sizeof(int) + sizeof(float)); // 1 MB
    const size_t XT_BYTES   = (size_t)IN_DIM * BATCH * sizeof(unsigned short);        // 32 MB
    const size_t NEED_FULL  = TAB_BYTES + XT_BYTES;

    if (ws_size >= NEED_FULL) {
        int*   idx_tab = (int*)d_ws;
        float* w_tab   = (float*)((char*)d_ws + (size_t)OUT_DIM * NACT * sizeof(int));
        unsigned short* xT = (unsigned short*)((char*)d_ws + TAB_BYTES);

        prep_kernel<<<OUT_DIM + (BATCH/64)*(IN_DIM/64), 256, 0, stream>>>(
            weight, mask, x, idx_tab, w_tab, xT);
        spmm_kernel<<<4096, 128, 0, stream>>>(xT, idx_tab, w_tab, bias, out);
    } else if (ws_size >= TAB_BYTES) {
        int*   idx_tab = (int*)d_ws;
        float* w_tab   = (float*)((char*)d_ws + (size_t)OUT_DIM * NACT * sizeof(int));
        prep_kernel<<<OUT_DIM, 256, 0, stream>>>(
            weight, mask, x, idx_tab, w_tab, (unsigned short*)nullptr);
        spmm_noT_kernel<<<4096, 256, 0, stream>>>(x, idx_tab, w_tab, bias, out);
    } else {
        naive_kernel<<<OUT_DIM, 256, 0, stream>>>(x, weight, bias, mask, out);
    }
}

// Round 10
// 91.471 us; speedup vs baseline: 1.1451x; 1.1451x over previous
//
#include <hip/hip_runtime.h>
#include <stdint.h>

#define IN_DIM  4096
#define OUT_DIM 4096
#define BATCH   4096
#define NACT    32

typedef float          f32x4  __attribute__((ext_vector_type(4)));
typedef unsigned short u16x4  __attribute__((ext_vector_type(4)));

// round-to-nearest f32 -> bf16
__device__ inline unsigned short f2bf(float f) {
    unsigned u = __float_as_uint(f);
    u += 0x7FFF + ((u >> 16) & 1);
    return (unsigned short)(u >> 16);
}

// ---------------------------------------------------------------------------
// Fused prep kernel (measured ~27us ~= its 160MB/6.3TB/s roofline).
//   blocks [0, OUT_DIM)              : compress mask+weight -> idx/w tables
//   blocks [OUT_DIM, OUT_DIM+4096)   : transpose x -> xT bf16 [IN_DIM][BATCH]
// ---------------------------------------------------------------------------
__global__ __launch_bounds__(256)
void prep_kernel(const float* __restrict__ weight,
                 const int*   __restrict__ mask,
                 const float* __restrict__ x,
                 int*         __restrict__ idx_tab,
                 float*       __restrict__ w_tab,
                 unsigned short* __restrict__ xT) {
    __shared__ float tile[64][65];        // transpose tile; aliased as scan[]
    int* scan = (int*)&tile[0][0];
    const int t = threadIdx.x;

    if (blockIdx.x < OUT_DIM) {
        // ---- compress: one block per output row ----
        const int o = blockIdx.x;
        const int* mrow = mask + (size_t)o * IN_DIM;
        const int  base = t * 16;

        int m[16];
        const int4* m4 = (const int4*)(mrow + base);
        #pragma unroll
        for (int j = 0; j < 4; ++j) {
            int4 v = m4[j];
            m[j*4+0] = v.x; m[j*4+1] = v.y; m[j*4+2] = v.z; m[j*4+3] = v.w;
        }
        int c = 0;
        #pragma unroll
        for (int j = 0; j < 16; ++j) c += (m[j] != 0);

        scan[t] = c;
        __syncthreads();
        for (int off = 1; off < 256; off <<= 1) {
            int add = (t >= off) ? scan[t - off] : 0;
            __syncthreads();
            scan[t] += add;
            __syncthreads();
        }
        int pos = scan[t] - c;            // exclusive prefix
        for (int j = 0; j < 16; ++j) {
            if (m[j] != 0) {
                int idx = base + j;
                idx_tab[o * NACT + pos] = idx;
                w_tab [o * NACT + pos] = weight[(size_t)o * IN_DIM + idx];
                ++pos;
            }
        }
    } else {
        // ---- transpose + bf16 quantize: 64x64 tile ----
        const int q  = blockIdx.x - OUT_DIM;
        const int bi = q & 63;            // batch tile
        const int bj = q >> 6;            // in-dim tile
        {
            const int c  = (t & 15) * 4;
            const int r0 = t >> 4;
            #pragma unroll
            for (int p = 0; p < 4; ++p) {
                int r = r0 + p * 16;
                float4 v = *(const float4*)(x + (size_t)(bi*64 + r) * IN_DIM + bj*64 + c);
                tile[r][c+0] = v.x; tile[r][c+1] = v.y;
                tile[r][c+2] = v.z; tile[r][c+3] = v.w;
            }
        }
        __syncthreads();
        {
            const int b4 = (t & 15) * 4;
            const int j0 = t >> 4;
            #pragma unroll
            for (int p = 0; p < 4; ++p) {
                int j = j0 + p * 16;
                u16x4 v = { f2bf(tile[b4+0][j]), f2bf(tile[b4+1][j]),
                            f2bf(tile[b4+2][j]), f2bf(tile[b4+3][j]) };
                *(u16x4*)(xT + (size_t)(bj*64 + j) * BATCH + bi*64 + b4) = v;
            }
        }
    }
}

// ---------------------------------------------------------------------------
// Main sparse matmul (r8 structure + occupancy + addressing fixes).
// Block = 128 threads; thread t = batches (2t, 2t+1) x 16 outputs.
// Slab = 256 batches x 4096 rows x 2B = 2 MB (L2-resident; r8 FETCH=36MB
// ~= compulsory; r9 proved plain stores re-pollute -> keep nt + restage).
// Gathers: uniform-row-base addressing — row = readfirstlane(ip[k]) keeps
// the row offset in SGPRs, so each gather is s_lshl/s_add (SALU) +
// global_load_dword with constant lane voffset: ~0 VALU per gather
// (r8 spent ~3 VALU/gather on per-lane 64-bit adds; VALUBusy 43%).
// Store: TWO-PASS restage through L[128][17] (8.7 KB, half of r8) ->
// LDS no longer caps occupancy (9 -> grid-capped 16 blocks/CU).
// Each pass: half the threads write their accs, all threads emit full
// 64B lines as f32x4 nt stores (nt keeps write stream out of L2).
// Grid = 16 slabs x 256 o-tiles; swizzle: each XCD sweeps o-tiles slab-major.
// ---------------------------------------------------------------------------
__global__ __launch_bounds__(128)
void spmm_kernel(const unsigned short* __restrict__ xT,
                 const int*   __restrict__ idx_tab,
                 const float* __restrict__ w_tab,
                 const float* __restrict__ bias,
                 float*       __restrict__ out) {
    const int t   = threadIdx.x;          // 0..127
    const int bid = blockIdx.x;           // 4096 blocks
    const int v    = (bid & 7) * 512 + (bid >> 3);   // bijective XCD swizzle
    const int slab = v >> 8;              // 0..15 (slab-major per XCD)
    const int ot   = v & 255;             // o-tile minor
    const int o0   = ot * 16;
    const int b0   = slab * 256;          // slab batch base
    const int bl   = t * 2;               // batch-local (even)

    const unsigned* xTd = (const unsigned*)xT;     // dword view (2 bf16/dword)
    const int bl2 = (b0 >> 1) + t;        // this thread's dword column

    float acc0[16], acc1[16];
    #pragma unroll 2
    for (int o = 0; o < 16; ++o) {
        const int*   ip = idx_tab + (size_t)(o0 + o) * NACT;   // wave-uniform
        const float* wp = w_tab   + (size_t)(o0 + o) * NACT;   // -> s_load
        float a00 = 0.f, a01 = 0.f, a10 = 0.f, a11 = 0.f;
        #pragma unroll
        for (int k = 0; k < NACT; k += 2) {
            int r0 = __builtin_amdgcn_readfirstlane(ip[k]);    // force SGPR
            int r1 = __builtin_amdgcn_readfirstlane(ip[k+1]);
            unsigned u0 = xTd[(size_t)r0 * (BATCH/2) + bl2];   // saddr + voff
            unsigned u1 = xTd[(size_t)r1 * (BATCH/2) + bl2];
            float x00 = __uint_as_float(u0 << 16);          // batch bl
            float x01 = __uint_as_float(u0 & 0xFFFF0000u);  // batch bl+1
            float x10 = __uint_as_float(u1 << 16);
            float x11 = __uint_as_float(u1 & 0xFFFF0000u);
            a00 = fmaf(wp[k],   x00, a00);
            a01 = fmaf(wp[k],   x01, a01);
            a10 = fmaf(wp[k+1], x10, a10);
            a11 = fmaf(wp[k+1], x11, a11);
        }
        const float bo = bias[o0 + o];
        acc0[o] = (a00 + a10) - bo;
        acc1[o] = (a01 + a11) - bo;
    }

    // ---- two-pass restage through LDS for full-line nt stores ----
    __shared__ float L[128 * 17];         // 8.7 KB: half-slab at a time
    #pragma unroll
    for (int h = 0; h < 2; ++h) {
        if ((t >> 6) == h) {              // wave-uniform branch
            const int r = bl & 127;       // row within half-slab
            #pragma unroll
            for (int o = 0; o < 16; ++o) {
                L[(r + 0) * 17 + o] = acc0[o];
                L[(r + 1) * 17 + o] = acc1[o];
            }
        }
        __syncthreads();
        const int rr = t >> 2;            // 0..31
        const int c  = (t & 3) * 4;       // 16B sub-line
        #pragma unroll
        for (int p = 0; p < 4; ++p) {
            int r = rr + p * 32;          // 0..127
            f32x4 rv = { L[r*17 + c+0], L[r*17 + c+1],
                         L[r*17 + c+2], L[r*17 + c+3] };
            __builtin_nontemporal_store(rv,
                (f32x4*)(out + (size_t)(b0 + h*128 + r) * OUT_DIM + o0 + c));
        }
        __syncthreads();                  // L reused by next pass
    }
}

// ---------------------------------------------------------------------------
// Fallback A (ws >= table only): gathers from x directly (uncoalesced, correct).
// ---------------------------------------------------------------------------
__global__ __launch_bounds__(256)
void spmm_noT_kernel(const float* __restrict__ x,
                     const int*   __restrict__ idx_tab,
                     const float* __restrict__ w_tab,
                     const float* __restrict__ bias,
                     float*       __restrict__ out) {
    const int t   = threadIdx.x;
    const int bid = blockIdx.x;           // 4096 blocks
    const int slab = bid >> 8;
    const int ot   = bid & 255;
    const int o0   = ot * 16;
    const int b    = slab * 256 + t;

    float acc[16];
    #pragma unroll 1
    for (int o = 0; o < 16; ++o) {
        const int*   ip = idx_tab + (size_t)(o0 + o) * NACT;
        const float* wp = w_tab   + (size_t)(o0 + o) * NACT;
        float a = 0.f;
        for (int k = 0; k < NACT; ++k)
            a = fmaf(wp[k], x[(size_t)b * IN_DIM + ip[k]], a);
        acc[o] = a - bias[o0 + o];
    }
    float* op = out + (size_t)b * OUT_DIM + o0;
    #pragma unroll
    for (int q = 0; q < 4; ++q) {
        float4 r; r.x = acc[q*4+0]; r.y = acc[q*4+1];
                  r.z = acc[q*4+2]; r.w = acc[q*4+3];
        *(float4*)(op + q*4) = r;
    }
}

// ---------------------------------------------------------------------------
// Fallback B (tiny ws): block per output row; inline compress into LDS.
// ---------------------------------------------------------------------------
__global__ __launch_bounds__(256)
void naive_kernel(const float* __restrict__ x,
                  const float* __restrict__ weight,
                  const float* __restrict__ bias,
                  const int*   __restrict__ mask,
                  float*       __restrict__ out) {
    const int o = blockIdx.x;
    const int t = threadIdx.x;
    __shared__ int   scan[256];
    __shared__ int   sidx[NACT];
    __shared__ float sw[NACT];

    const int* mrow = mask + (size_t)o * IN_DIM;
    const int  base = t * 16;
    int c = 0;
    #pragma unroll
    for (int j = 0; j < 16; ++j) c += (mrow[base + j] != 0);
    scan[t] = c;
    __syncthreads();
    for (int off = 1; off < 256; off <<= 1) {
        int add = (t >= off) ? scan[t - off] : 0;
        __syncthreads();
        scan[t] += add;
        __syncthreads();
    }
    int pos = scan[t] - c;
    for (int j = 0; j < 16; ++j) {
        if (mrow[base + j] != 0) {
            sidx[pos] = base + j;
            sw[pos]   = weight[(size_t)o * IN_DIM + base + j];
            ++pos;
        }
    }
    __syncthreads();
    const float bo = bias[o];
    for (int b = t; b < BATCH; b += 256) {
        float a = 0.f;
        #pragma unroll
        for (int k = 0; k < NACT; ++k)
            a = fmaf(sw[k], x[(size_t)b * IN_DIM + sidx[k]], a);
        out[(size_t)b * OUT_DIM + o] = a - bo;
    }
}

// ---------------------------------------------------------------------------
extern "C" void kernel_launch(void* const* d_in, const int* in_sizes, int n_in,
                              void* d_out, int out_size, void* d_ws, size_t ws_size,
                              hipStream_t stream) {
    const float* x      = (const float*)d_in[0];
    const float* weight = (const float*)d_in[1];
    const float* bias   = (const float*)d_in[2];
    const int*   mask   = (const int*)  d_in[3];
    float* out = (float*)d_out;

    const size_t TAB_BYTES  = (size_t)OUT_DIM * NACT * (sizeof(int) + sizeof(float)); // 1 MB
    const size_t XT_BYTES   = (size_t)IN_DIM * BATCH * sizeof(unsigned short);        // 32 MB
    const size_t NEED_FULL  = TAB_BYTES + XT_BYTES;

    if (ws_size >= NEED_FULL) {
        int*   idx_tab = (int*)d_ws;
        float* w_tab   = (float*)((char*)d_ws + (size_t)OUT_DIM * NACT * sizeof(int));
        unsigned short* xT = (unsigned short*)((char*)d_ws + TAB_BYTES);

        prep_kernel<<<OUT_DIM + (BATCH/64)*(IN_DIM/64), 256, 0, stream>>>(
            weight, mask, x, idx_tab, w_tab, xT);
        spmm_kernel<<<4096, 128, 0, stream>>>(xT, idx_tab, w_tab, bias, out);
    } else if (ws_size >= TAB_BYTES) {
        int*   idx_tab = (int*)d_ws;
        float* w_tab   = (float*)((char*)d_ws + (size_t)OUT_DIM * NACT * sizeof(int));
        prep_kernel<<<OUT_DIM, 256, 0, stream>>>(
            weight, mask, x, idx_tab, w_tab, (unsigned short*)nullptr);
        spmm_noT_kernel<<<4096, 256, 0, stream>>>(x, idx_tab, w_tab, bias, out);
    } else {
        naive_kernel<<<OUT_DIM, 256, 0, stream>>>(x, weight, bias, mask, out);
    }
}